// Round 1
// baseline (3194.943 us; speedup 1.0000x reference)
//
#include <hip/hip_runtime.h>
#include <stdint.h>

// Farthest-point sampling (N=100000, M=1024) + feat/coord gather.
// Latency-bound: 1023 sequential argmax steps. All point state lives in
// registers of a 32-block persistent kernel; blocks handshake once per
// iteration via device-scope atomics on parity-double-buffered, tag-stamped
// slots in d_ws.

#define N_PTS   100000
#define M_SEL   1024
#define NBLK    32
#define NTHR    256
#define TOT     (NBLK * NTHR)                 // 8192 threads
#define PPT     13                            // ceil(100000/8192)
#define REMTH   (N_PTS - (PPT - 1) * TOT)     // 1696: threads g<1696 own a 13th point

typedef unsigned long long u64;

__device__ __forceinline__ u64 u64max(u64 a, u64 b) { return a > b ? a : b; }

// 64-bit shuffle via two 32-bit shuffles (guaranteed-available int overload).
__device__ __forceinline__ u64 shflxor_u64(u64 v, int m, int w) {
    int lo = (int)(unsigned)v;
    int hi = (int)(unsigned)(v >> 32);
    lo = __shfl_xor(lo, m, w);
    hi = __shfl_xor(hi, m, w);
    return ((u64)(unsigned)hi << 32) | (u64)(unsigned)lo;
}

// Zero the 2*NBLK handshake slots (d_ws is poisoned 0xAA before every launch)
// and emit idx[0] = 0 (reference starts from index 0).
__global__ __launch_bounds__(64) void fps_init(u64* slots, int* idx_out) {
    int i = threadIdx.x;
    slots[i] = 0ull;
    if (i == 0) idx_out[0] = 0;
}

__global__ __launch_bounds__(NTHR) void fps_kernel(const float* __restrict__ coord,
                                                   u64* __restrict__ slots,
                                                   int* __restrict__ idx_out) {
    const int tid = threadIdx.x;
    const int bid = blockIdx.x;
    const int g   = bid * NTHR + tid;

    // Per-thread point state, fully in registers.
    float px[PPT], py[PPT], pz[PPT], dmin[PPT];
#pragma unroll
    for (int t = 0; t < PPT; ++t) {
        const bool ok = (t < PPT - 1) || (g < REMTH);
        const int  p  = ok ? (g + t * TOT) : 0;
        px[t]  = coord[3 * p + 0];
        py[t]  = coord[3 * p + 1];
        pz[t]  = coord[3 * p + 2];
        dmin[t] = 1e10f;  // matches jnp.full((N,), 1e10)
    }

    __shared__ u64 s_wbest[NTHR / 64];
    __shared__ int s_fid;

    int fid = 0;  // reference fixes the start index at 0
    for (int it = 1; it < M_SEL; ++it) {
        // Centroid of current farthest point (uniform address, L2-resident).
        const float cx = coord[3 * fid + 0];
        const float cy = coord[3 * fid + 1];
        const float cz = coord[3 * fid + 2];

        // Update running min distances; track local best as a packed key.
        // Key: dist_bits(32) << 17 | (131071 - idx)  — larger dist wins,
        // equal dist -> smaller idx (jnp.argmax first-max semantics).
        // Distance math mirrors XLA: separate mul/add roundings (no FMA).
        u64 best = 0;
#pragma unroll
        for (int t = 0; t < PPT; ++t) {
            const float dx = px[t] - cx;
            const float dy = py[t] - cy;
            const float dz = pz[t] - cz;
            const float d  = __fadd_rn(__fadd_rn(__fmul_rn(dx, dx), __fmul_rn(dy, dy)),
                                       __fmul_rn(dz, dz));
            const float nd = fminf(dmin[t], d);
            dmin[t] = nd;
            const bool ok = (t < PPT - 1) || (g < REMTH);
            if (ok) {
                const int p   = g + t * TOT;
                const u64 key = ((u64)__float_as_uint(nd) << 17) | (u64)(131071 - p);
                if (key > best) best = key;
            }
        }

        // Wave reduce (64 lanes).
#pragma unroll
        for (int m = 32; m >= 1; m >>= 1)
            best = u64max(best, shflxor_u64(best, m, 64));

        const int wid = tid >> 6;
        if ((tid & 63) == 0) s_wbest[wid] = best;
        __syncthreads();

        if (wid == 0) {
            // Block reduce across 4 waves.
            u64 b2 = (tid < NTHR / 64) ? s_wbest[tid] : 0;
#pragma unroll
            for (int m = (NTHR / 64) >> 1; m >= 1; m >>= 1)
                b2 = u64max(b2, shflxor_u64(b2, m, NTHR / 64));

            // Publish tagged key; parity double-buffer kills ABA hazards.
            const u64 tagged = ((u64)it << 49) | b2;
            u64* base = &slots[(u64)(it & 1) * NBLK];
            if (tid == 0)
                __hip_atomic_store(&base[bid], tagged, __ATOMIC_RELEASE,
                                   __HIP_MEMORY_SCOPE_AGENT);

            // Lanes 0..31 each spin on one block's slot until its tag == it.
            u64 v = 0;
            if (tid < NBLK) {
                u64* sp = &base[tid];
                do {
                    v = __hip_atomic_load(sp, __ATOMIC_ACQUIRE,
                                          __HIP_MEMORY_SCOPE_AGENT);
                } while ((int)(v >> 49) != it);
            }
            // Redundant 32-way reduce: every block derives the winner itself.
#pragma unroll
            for (int m = NBLK >> 1; m >= 1; m >>= 1)
                v = u64max(v, shflxor_u64(v, m, NBLK));

            if (tid == 0) {
                const int f = 131071 - (int)(v & 0x1FFFF);
                s_fid = f;
                if (bid == 0) idx_out[it] = f;
            }
        }
        __syncthreads();
        fid = s_fid;
    }
}

// out[0 .. 524287]        = feat[idx]  (1024 x 512)
// out[524288 .. 527359]   = coord[idx] (1024 x 3)
__global__ __launch_bounds__(128) void gather_kernel(const float* __restrict__ feat,
                                                     const float* __restrict__ coord,
                                                     const int* __restrict__ idx,
                                                     float* __restrict__ out) {
    const int m = blockIdx.x;
    const int f = idx[m];
    const int t = threadIdx.x;
    const float4* src = (const float4*)(feat + (size_t)f * 512);
    float4*       dst = (float4*)(out + (size_t)m * 512);
    dst[t] = src[t];  // 128 threads x float4 = 512 floats
    if (t < 3) out[(size_t)M_SEL * 512 + m * 3 + t] = coord[f * 3 + t];
}

extern "C" void kernel_launch(void* const* d_in, const int* in_sizes, int n_in,
                              void* d_out, int out_size, void* d_ws, size_t ws_size,
                              hipStream_t stream) {
    const float* feat  = (const float*)d_in[0];   // (100000, 512) f32
    const float* coord = (const float*)d_in[1];   // (100000, 3)   f32
    float* out = (float*)d_out;

    // ws layout: [0,512) handshake slots (2*NBLK u64); [512,4608) idx int32[1024]
    u64* slots = (u64*)d_ws;
    int* idx   = (int*)((char*)d_ws + 512);

    fps_init<<<1, 64, 0, stream>>>(slots, idx);
    fps_kernel<<<NBLK, NTHR, 0, stream>>>(coord, slots, idx);
    gather_kernel<<<M_SEL, 128, 0, stream>>>(feat, coord, idx, out);
}

// Round 2
// 2794.298 us; speedup vs baseline: 1.1434x; 1.1434x over previous
//
#include <hip/hip_runtime.h>
#include <stdint.h>

// Farthest-point sampling (N=100000, M=1024) + feat/coord gather.
// Latency-bound: 1023 sequential argmax steps. All point state lives in
// registers of a 32-block persistent kernel; blocks handshake once per
// iteration via RELAXED device-scope atomics on parity-double-buffered,
// tag-stamped 64-bit slots in d_ws. Payload (tag|dist|idx) fits in one
// 64-bit word, so no acquire/release fences are needed -> no per-poll
// cache invalidates, coord stays L1/L2-resident.

#define N_PTS   100000
#define M_SEL   1024
#define NBLK    32
#define NTHR    256
#define TOT     (NBLK * NTHR)                 // 8192 threads
#define PPT     13                            // ceil(100000/8192)
#define REMTH   (N_PTS - (PPT - 1) * TOT)     // 1696: threads g<1696 own a 13th point

typedef unsigned long long u64;

__device__ __forceinline__ u64 u64max(u64 a, u64 b) { return a > b ? a : b; }

// 64-bit shuffle via two 32-bit shuffles.
__device__ __forceinline__ u64 shflxor_u64(u64 v, int m, int w) {
    int lo = (int)(unsigned)v;
    int hi = (int)(unsigned)(v >> 32);
    lo = __shfl_xor(lo, m, w);
    hi = __shfl_xor(hi, m, w);
    return ((u64)(unsigned)hi << 32) | (u64)(unsigned)lo;
}

// Zero the 2*NBLK handshake slots (d_ws is poisoned 0xAA before every launch)
// and emit idx[0] = 0 (reference starts from index 0).
__global__ __launch_bounds__(64) void fps_init(u64* slots, int* idx_out) {
    int i = threadIdx.x;
    slots[i] = 0ull;
    if (i == 0) idx_out[0] = 0;
}

__global__ __launch_bounds__(NTHR) void fps_kernel(const float* __restrict__ coord,
                                                   u64* __restrict__ slots,
                                                   int* __restrict__ idx_out) {
    const int tid = threadIdx.x;
    const int bid = blockIdx.x;
    const int g   = bid * NTHR + tid;

    // Per-thread point state, fully in registers.
    float px[PPT], py[PPT], pz[PPT], dmin[PPT];
#pragma unroll
    for (int t = 0; t < PPT; ++t) {
        const bool ok = (t < PPT - 1) || (g < REMTH);
        const int  p  = ok ? (g + t * TOT) : 0;
        px[t]  = coord[3 * p + 0];
        py[t]  = coord[3 * p + 1];
        pz[t]  = coord[3 * p + 2];
        dmin[t] = 1e10f;  // matches jnp.full((N,), 1e10)
    }

    __shared__ u64 s_wbest[NTHR / 64];
    __shared__ int s_fid;

    int fid = 0;  // reference fixes the start index at 0
    for (int it = 1; it < M_SEL; ++it) {
        // Centroid of current farthest point (uniform address; with no
        // invalidates in the loop this stays L1/L2-resident).
        const float cx = coord[3 * fid + 0];
        const float cy = coord[3 * fid + 1];
        const float cz = coord[3 * fid + 2];

        // Update running min distances; track local best as a packed key.
        // Key: dist_bits(32) << 17 | (131071 - idx)  — larger dist wins,
        // equal dist -> smaller idx (jnp.argmax first-max semantics).
        // Distance math mirrors XLA: separate mul/add roundings (no FMA).
        u64 best = 0;
#pragma unroll
        for (int t = 0; t < PPT; ++t) {
            const float dx = px[t] - cx;
            const float dy = py[t] - cy;
            const float dz = pz[t] - cz;
            const float d  = __fadd_rn(__fadd_rn(__fmul_rn(dx, dx), __fmul_rn(dy, dy)),
                                       __fmul_rn(dz, dz));
            const float nd = fminf(dmin[t], d);
            dmin[t] = nd;
            const bool ok = (t < PPT - 1) || (g < REMTH);
            if (ok) {
                const int p   = g + t * TOT;
                const u64 key = ((u64)__float_as_uint(nd) << 17) | (u64)(131071 - p);
                if (key > best) best = key;
            }
        }

        // Wave reduce (64 lanes).
#pragma unroll
        for (int m = 32; m >= 1; m >>= 1)
            best = u64max(best, shflxor_u64(best, m, 64));

        const int wid = tid >> 6;
        if ((tid & 63) == 0) s_wbest[wid] = best;
        __syncthreads();

        if (wid == 0) {
            // Block reduce across 4 waves.
            u64 b2 = (tid < NTHR / 64) ? s_wbest[tid] : 0;
#pragma unroll
            for (int m = (NTHR / 64) >> 1; m >= 1; m >>= 1)
                b2 = u64max(b2, shflxor_u64(b2, m, NTHR / 64));

            // Publish tagged key; parity double-buffer + monotonic tag kills
            // ABA hazards. RELAXED: payload is inside the same 64-bit word,
            // no fences / cache maintenance needed.
            const u64 tagged = ((u64)it << 49) | b2;
            u64* base = &slots[(u64)(it & 1) * NBLK];
            if (tid == 0)
                __hip_atomic_store(&base[bid], tagged, __ATOMIC_RELAXED,
                                   __HIP_MEMORY_SCOPE_AGENT);

            // Lanes 0..31 each spin on one block's slot until its tag == it.
            u64 v = 0;
            if (tid < NBLK) {
                u64* sp = &base[tid];
                do {
                    v = __hip_atomic_load(sp, __ATOMIC_RELAXED,
                                          __HIP_MEMORY_SCOPE_AGENT);
                } while ((int)(v >> 49) != it);
            }
            // Redundant 32-way reduce: every block derives the winner itself.
#pragma unroll
            for (int m = NBLK >> 1; m >= 1; m >>= 1)
                v = u64max(v, shflxor_u64(v, m, NBLK));

            if (tid == 0) {
                const int f = 131071 - (int)(v & 0x1FFFF);
                s_fid = f;
                if (bid == 0) idx_out[it] = f;
            }
        }
        __syncthreads();
        fid = s_fid;
    }
}

// out[0 .. 524287]        = feat[idx]  (1024 x 512)
// out[524288 .. 527359]   = coord[idx] (1024 x 3)
__global__ __launch_bounds__(128) void gather_kernel(const float* __restrict__ feat,
                                                     const float* __restrict__ coord,
                                                     const int* __restrict__ idx,
                                                     float* __restrict__ out) {
    const int m = blockIdx.x;
    const int f = idx[m];
    const int t = threadIdx.x;
    const float4* src = (const float4*)(feat + (size_t)f * 512);
    float4*       dst = (float4*)(out + (size_t)m * 512);
    dst[t] = src[t];  // 128 threads x float4 = 512 floats
    if (t < 3) out[(size_t)M_SEL * 512 + m * 3 + t] = coord[f * 3 + t];
}

extern "C" void kernel_launch(void* const* d_in, const int* in_sizes, int n_in,
                              void* d_out, int out_size, void* d_ws, size_t ws_size,
                              hipStream_t stream) {
    const float* feat  = (const float*)d_in[0];   // (100000, 512) f32
    const float* coord = (const float*)d_in[1];   // (100000, 3)   f32
    float* out = (float*)d_out;

    // ws layout: [0,512) handshake slots (2*NBLK u64); [512,4608) idx int32[1024]
    u64* slots = (u64*)d_ws;
    int* idx   = (int*)((char*)d_ws + 512);

    fps_init<<<1, 64, 0, stream>>>(slots, idx);
    fps_kernel<<<NBLK, NTHR, 0, stream>>>(coord, slots, idx);
    gather_kernel<<<M_SEL, 128, 0, stream>>>(feat, coord, idx, out);
}